// Round 3
// baseline (401.290 us; speedup 1.0000x reference)
//
#include <hip/hip_runtime.h>

#define B_ 16384
#define D_ 2048
#define P_ 64
#define K_ 5

// ---------------------------------------------------------------------------
// K0: transpose parent_W [P=64][D=2048] -> wT [D][P] in workspace (512 KB).
// Lets k1 read W fragments directly from L2 with contiguous 32B per lane,
// keeping the LDS pipe free for the x operand.
// ---------------------------------------------------------------------------
__global__ __launch_bounds__(256) void k0_transpose(const float* __restrict__ W,
                                                    float* __restrict__ wT) {
  const int i  = blockIdx.x * 256 + threadIdx.x;  // 0..32767
  const int c  = i >> 9;                          // 0..63
  const int d0 = (i & 511) << 2;                  // 0..2044
  const float4 v = *(const float4*)&W[c * D_ + d0];
  wT[(d0 + 0) * P_ + c] = v.x;
  wT[(d0 + 1) * P_ + c] = v.y;
  wT[(d0 + 2) * P_ + c] = v.z;
  wT[(d0 + 3) * P_ + c] = v.w;
}

// ---------------------------------------------------------------------------
// K1: parent GEMM partials. grid = 256 row-tiles x KS k-splits, 64 thr (1 wave).
// Block: 64 rows x 64 cols over k-range [ks*kslice, +kslice). 8x8 acc/lane.
// x: global->regs->LDS transposed (2-way bank access = free); W: direct L2.
// Per d-iter/wave: 2 ds_read_b128 (24cy) + 2 L2 dwordx4 + 64 v_fma (128cy)
// -> FMA-bound. Single-wave blocks: __syncthreads is just a waitcnt.
// ---------------------------------------------------------------------------
__global__ __launch_bounds__(64) void k1_parent(const float* __restrict__ x,
                                                const float* __restrict__ wT,
                                                float* __restrict__ part,
                                                int kslice) {
  __shared__ float xT[32 * 64];  // 8 KB: xT[d][row], d in chunk of 32
  const int t   = threadIdx.x;
  const int rt  = blockIdx.x & 255;
  const int ks  = blockIdx.x >> 8;
  const int b0  = rt * 64;
  const int kbase = ks * kslice;
  const int lr8 = (t >> 3) << 3;  // row base
  const int lc8 = (t & 7) << 3;   // col base

  const float* xrow = x + (size_t)(b0 + t) * D_ + kbase;

  float4 acc[8][2];
#pragma unroll
  for (int i = 0; i < 8; ++i) {
    acc[i][0] = make_float4(0.f, 0.f, 0.f, 0.f);
    acc[i][1] = make_float4(0.f, 0.f, 0.f, 0.f);
  }

  const int nch = kslice >> 5;
  float4 st[8];
#pragma unroll
  for (int j = 0; j < 8; ++j) st[j] = *(const float4*)&xrow[j * 4];

  for (int ch = 0; ch < nch; ++ch) {
    // stage regs -> LDS (transpose): instr j writes 64 consecutive floats
#pragma unroll
    for (int j = 0; j < 8; ++j) {
      xT[(4 * j + 0) * 64 + t] = st[j].x;
      xT[(4 * j + 1) * 64 + t] = st[j].y;
      xT[(4 * j + 2) * 64 + t] = st[j].z;
      xT[(4 * j + 3) * 64 + t] = st[j].w;
    }
    __syncthreads();
    if (ch + 1 < nch) {
      const float* nx = xrow + (ch + 1) * 32;
#pragma unroll
      for (int j = 0; j < 8; ++j) st[j] = *(const float4*)&nx[j * 4];
    }
    const float* wd = wT + (size_t)(kbase + (ch << 5)) * P_;
#pragma unroll 4
    for (int d = 0; d < 32; ++d) {
      const float4 xv0 = *(const float4*)&xT[d * 64 + lr8];
      const float4 xv1 = *(const float4*)&xT[d * 64 + lr8 + 4];
      const float4 wv0 = *(const float4*)&wd[d * 64 + lc8];
      const float4 wv1 = *(const float4*)&wd[d * 64 + lc8 + 4];
      const float xs[8] = {xv0.x, xv0.y, xv0.z, xv0.w,
                           xv1.x, xv1.y, xv1.z, xv1.w};
#pragma unroll
      for (int i = 0; i < 8; ++i) {
        acc[i][0].x += xs[i] * wv0.x; acc[i][0].y += xs[i] * wv0.y;
        acc[i][0].z += xs[i] * wv0.z; acc[i][0].w += xs[i] * wv0.w;
        acc[i][1].x += xs[i] * wv1.x; acc[i][1].y += xs[i] * wv1.y;
        acc[i][1].z += xs[i] * wv1.z; acc[i][1].w += xs[i] * wv1.w;
      }
    }
    __syncthreads();
  }

  float* po = part + (size_t)ks * (B_ * P_) + (size_t)b0 * P_;
#pragma unroll
  for (int i = 0; i < 8; ++i) {
    *(float4*)&po[(size_t)(lr8 + i) * P_ + lc8]     = acc[i][0];
    *(float4*)&po[(size_t)(lr8 + i) * P_ + lc8 + 4] = acc[i][1];
  }
}

// ---------------------------------------------------------------------------
// Kred: pout = sum(partials) + bias; wave-wide argmax (tie -> lower index,
// matching jnp.argmax); builds per-expert row lists for k2 via atomics.
// One wave per row; grid 4096 x 256.
// ---------------------------------------------------------------------------
__global__ __launch_bounds__(256) void k_reduce(const float* __restrict__ part,
                                                const float* __restrict__ pb,
                                                float* __restrict__ pout,
                                                int* __restrict__ cnt,
                                                int* __restrict__ list,
                                                int KS) {
  const int wave = threadIdx.x >> 6, lane = threadIdx.x & 63;
  const int r = blockIdx.x * 4 + wave;
  float v = pb[lane];
  for (int s = 0; s < KS; ++s)
    v += part[(size_t)s * (B_ * P_) + (size_t)r * P_ + lane];
  pout[(size_t)r * P_ + lane] = v;

  float bv = v;
  int bi = lane;
#pragma unroll
  for (int s = 32; s > 0; s >>= 1) {
    const float ov = __shfl_xor(bv, s, 64);
    const int oi = __shfl_xor(bi, s, 64);
    if (ov > bv || (ov == bv && oi < bi)) { bv = ov; bi = oi; }
  }
  if (lane == 0) {
    const int slot = atomicAdd(&cnt[bi], 1);
    if (slot < 512) list[bi * 512 + slot] = r;
  }
}

// ---------------------------------------------------------------------------
// K2: child logits from dense row lists. grid = 64 experts x 8 chunks.
// W_e (40 KB) staged in LDS once per block; 4 rows batched per W pass
// (LDS instr/row cut 4x); pair-packed butterfly reduce (7 shfl per 2 accs).
// ---------------------------------------------------------------------------
__global__ __launch_bounds__(256) void k2_child(const float* __restrict__ x,
                                                const float* __restrict__ cW,
                                                const float* __restrict__ cb,
                                                const int* __restrict__ cnt,
                                                const int* __restrict__ list,
                                                float* __restrict__ cout) {
  __shared__ float wlds[K_ * D_];  // 40 KB
  const int e   = blockIdx.x >> 3;
  const int chk = blockIdx.x & 7;
  const int tid = threadIdx.x;

  const float4* wg4 = (const float4*)(cW + (size_t)e * (K_ * D_));
  float4* wl4 = (float4*)wlds;
#pragma unroll
  for (int tI = 0; tI < 10; ++tI) wl4[tid + 256 * tI] = wg4[tid + 256 * tI];
  __syncthreads();

  const int n   = min(cnt[e], 512);
  const int per = (n + 7) >> 3;
  const int lo  = chk * per;
  const int hi  = min(lo + per, n);
  const int m   = hi - lo;
  if (m <= 0) return;

  const int wave = tid >> 6, lane = tid & 63;
  const int wper = (m + 3) >> 2;
  const int wlo  = lo + wave * wper;
  const int whi  = min(wlo + wper, hi);

  const float4* x4 = (const float4*)x;
  const int* mylist = list + e * 512;

  for (int i0 = wlo; i0 < whi; i0 += 4) {
    const int vb = min(4, whi - i0);
    const int ra = mylist[i0];
    const int rb = mylist[i0 + min(1, vb - 1)];
    const int rc = mylist[i0 + min(2, vb - 1)];
    const int rd = mylist[i0 + min(3, vb - 1)];

    float a[20];
#pragma unroll
    for (int q = 0; q < 20; ++q) a[q] = 0.f;

#pragma unroll
    for (int tt = 0; tt < 8; ++tt) {
      const float4 xv0 = x4[(size_t)ra * 512 + lane + 64 * tt];
      const float4 xv1 = x4[(size_t)rb * 512 + lane + 64 * tt];
      const float4 xv2 = x4[(size_t)rc * 512 + lane + 64 * tt];
      const float4 xv3 = x4[(size_t)rd * 512 + lane + 64 * tt];
#pragma unroll
      for (int k = 0; k < 5; ++k) {
        const float4 wv = wl4[k * 512 + lane + 64 * tt];
        a[0 * 5 + k] += xv0.x * wv.x + xv0.y * wv.y + xv0.z * wv.z + xv0.w * wv.w;
        a[1 * 5 + k] += xv1.x * wv.x + xv1.y * wv.y + xv1.z * wv.z + xv1.w * wv.w;
        a[2 * 5 + k] += xv2.x * wv.x + xv2.y * wv.y + xv2.z * wv.z + xv2.w * wv.w;
        a[3 * 5 + k] += xv3.x * wv.x + xv3.y * wv.y + xv3.z * wv.z + xv3.w * wv.w;
      }
    }
    // pair-packed reduce: after s=32, both halves hold identical pair-sums,
    // so pack acc[2p] in lanes<32 and acc[2p+1] in lanes>=32, share 5 levels.
#pragma unroll
    for (int p = 0; p < 10; ++p) {
      float va = a[2 * p], vb2 = a[2 * p + 1];
      va  += __shfl_xor(va, 32, 64);
      vb2 += __shfl_xor(vb2, 32, 64);
      float z = (lane < 32) ? va : vb2;
      z += __shfl_xor(z, 16, 64);
      z += __shfl_xor(z, 8, 64);
      z += __shfl_xor(z, 4, 64);
      z += __shfl_xor(z, 2, 64);
      z += __shfl_xor(z, 1, 64);
      a[2 * p] = z;  // lanes<32: sum(acc[2p]); lanes>=32: sum(acc[2p+1])
    }
    if (lane == 0 || lane == 32) {
      const int off = (lane == 32) ? 1 : 0;
#pragma unroll
      for (int p = 0; p < 10; ++p) {
        const int f = 2 * p + off;
        const int rr = f / 5, kk = f % 5;
        if (rr < vb) {
          const int r = (rr == 0) ? ra : (rr == 1) ? rb : (rr == 2) ? rc : rd;
          cout[(size_t)r * K_ + kk] = a[2 * p] + cb[e * K_ + kk];
        }
      }
    }
  }
}

extern "C" void kernel_launch(void* const* d_in, const int* in_sizes, int n_in,
                              void* d_out, int out_size, void* d_ws, size_t ws_size,
                              hipStream_t stream) {
  const float* x  = (const float*)d_in[0];
  const float* pW = (const float*)d_in[1];
  const float* pb = (const float*)d_in[2];
  const float* cW = (const float*)d_in[3];
  const float* cb = (const float*)d_in[4];
  float* pout = (float*)d_out;                    // [B, 64]
  float* cout = (float*)d_out + (size_t)B_ * P_;  // [B, 5]

  char* ws = (char*)d_ws;
  float* wT   = (float*)ws;                 // 512 KB
  int*   cnt  = (int*)(ws + 524288);        // 256 B (padded to 4 KB)
  int*   list = (int*)(ws + 528384);        // 128 KB
  const size_t part_off = 1048576;
  const size_t part_bytes = (size_t)B_ * P_ * sizeof(float);  // 4 MB per split

  // Pick largest split-K whose partial buffers fit the workspace.
  int KS = 1;
  float* part = pout;  // KS=1 fallback: write raw sums into pout, reduce in place
  for (int cand = 8; cand >= 2; cand >>= 1) {
    if (part_off + (size_t)cand * part_bytes <= ws_size) {
      KS = cand;
      part = (float*)(ws + part_off);
      break;
    }
  }
  const int kslice = D_ / KS;

  hipMemsetAsync(cnt, 0, 64 * sizeof(int), stream);
  k0_transpose<<<128, 256, 0, stream>>>(pW, wT);
  k1_parent<<<256 * KS, 64, 0, stream>>>(x, wT, part, kslice);
  k_reduce<<<B_ / 4, 256, 0, stream>>>(part, pb, pout, cnt, list, KS);
  k2_child<<<P_ * 8, 256, 0, stream>>>(x, cW, cb, cnt, list, cout);
}

// Round 4
// 267.582 us; speedup vs baseline: 1.4997x; 1.4997x over previous
//
#include <hip/hip_runtime.h>

#define B_ 16384
#define D_ 2048
#define P_ 64
#define K_ 5

#define BM 64
#define BK 64
#define KS 4
#define KSLICE (D_ / KS)   // 512
#define NCH (KSLICE / BK)  // 8

// ---------------------------------------------------------------------------
// K1: parent GEMM partials. grid = 256 row-tiles x KS k-splits, 256 threads.
// Round-2 measured-clean body (VGPR=64, no spill, swizzled LDS, reg prefetch);
// split-K gives 4 independent blocks/CU (16 waves) so one block's barrier
// hides under the others' FMA. Writes acc (no bias) to part[ks][B][P].
// ---------------------------------------------------------------------------
__global__ __launch_bounds__(256) void k1_parent(
    const float* __restrict__ x, const float* __restrict__ pW,
    float* __restrict__ part) {
  __shared__ float smem[BK * BM + BK * P_];  // 24 KB
  float* xT = smem;
  float* wT = smem + BK * BM;

  const int tid = threadIdx.x;
  const int rt  = blockIdx.x & 255;
  const int ks  = blockIdx.x >> 8;
  const int b0  = rt * BM;
  const int kbase = ks * KSLICE;
  const int q   = tid & 15;
  const int rw  = tid >> 4;
  const int tc4 = (tid & 15) << 2;
  const int tr4 = (tid >> 4) << 2;

  const float* xg = x + (size_t)b0 * D_ + kbase;
  const float* wg = pW + kbase;

  float4 xa[4], wb[4];
#pragma unroll
  for (int j = 0; j < 4; ++j) {
    xa[j] = *(const float4*)&xg[(size_t)(rw + 16 * j) * D_ + (q << 2)];
    wb[j] = *(const float4*)&wg[(size_t)(rw + 16 * j) * D_ + (q << 2)];
  }

  float acc[4][4];
#pragma unroll
  for (int i = 0; i < 4; ++i)
#pragma unroll
    for (int jj = 0; jj < 4; ++jj) acc[i][jj] = 0.f;

  const int swz = q << 2;
  for (int kk = 0; kk < NCH; ++kk) {
#pragma unroll
    for (int j = 0; j < 4; ++j) {
      const int cx = (rw + 16 * j) ^ swz;
      xT[(4 * q + 0) * BM + cx] = xa[j].x;
      xT[(4 * q + 1) * BM + cx] = xa[j].y;
      xT[(4 * q + 2) * BM + cx] = xa[j].z;
      xT[(4 * q + 3) * BM + cx] = xa[j].w;
      wT[(4 * q + 0) * P_ + cx] = wb[j].x;
      wT[(4 * q + 1) * P_ + cx] = wb[j].y;
      wT[(4 * q + 2) * P_ + cx] = wb[j].z;
      wT[(4 * q + 3) * P_ + cx] = wb[j].w;
    }
    __syncthreads();
    if (kk + 1 < NCH) {
      const int d0 = (kk + 1) * BK;
#pragma unroll
      for (int j = 0; j < 4; ++j) {
        xa[j] = *(const float4*)&xg[(size_t)(rw + 16 * j) * D_ + d0 + (q << 2)];
        wb[j] = *(const float4*)&wg[(size_t)(rw + 16 * j) * D_ + d0 + (q << 2)];
      }
    }
#pragma unroll 8
    for (int d = 0; d < BK; ++d) {
      const int sz = ((d >> 2) & 15) << 2;
      const float4 xv = *(const float4*)&xT[d * BM + (tr4 ^ sz)];
      const float4 wv = *(const float4*)&wT[d * P_ + (tc4 ^ sz)];
      acc[0][0] += xv.x * wv.x; acc[0][1] += xv.x * wv.y;
      acc[0][2] += xv.x * wv.z; acc[0][3] += xv.x * wv.w;
      acc[1][0] += xv.y * wv.x; acc[1][1] += xv.y * wv.y;
      acc[1][2] += xv.y * wv.z; acc[1][3] += xv.y * wv.w;
      acc[2][0] += xv.z * wv.x; acc[2][1] += xv.z * wv.y;
      acc[2][2] += xv.z * wv.z; acc[2][3] += xv.z * wv.w;
      acc[3][0] += xv.w * wv.x; acc[3][1] += xv.w * wv.y;
      acc[3][2] += xv.w * wv.z; acc[3][3] += xv.w * wv.w;
    }
    __syncthreads();
  }

  float* po = part + (size_t)ks * (B_ * P_) + (size_t)b0 * P_;
#pragma unroll
  for (int i = 0; i < 4; ++i) {
    float4 v;
    v.x = acc[i][0]; v.y = acc[i][1]; v.z = acc[i][2]; v.w = acc[i][3];
    *(float4*)&po[(size_t)(tr4 + i) * P_ + tc4] = v;
  }
}

// ---------------------------------------------------------------------------
// Kred: pout = sum(4 partials) + bias; wave argmax (tie -> lower index);
// per-expert row lists. cnt padded to 64B/counter: 64 parallel L2 lines,
// ~256 serialized adds each (was 4096/line -> O(100us) in round 3).
// ---------------------------------------------------------------------------
__global__ __launch_bounds__(256) void k_reduce(const float* __restrict__ part,
                                                const float* __restrict__ pb,
                                                float* __restrict__ pout,
                                                int* __restrict__ cnt,
                                                int* __restrict__ list) {
  const int wave = threadIdx.x >> 6, lane = threadIdx.x & 63;
  const int r = blockIdx.x * 4 + wave;
  float v = pb[lane];
#pragma unroll
  for (int s = 0; s < KS; ++s)
    v += part[(size_t)s * (B_ * P_) + (size_t)r * P_ + lane];
  pout[(size_t)r * P_ + lane] = v;

  float bv = v;
  int bi = lane;
#pragma unroll
  for (int s = 32; s > 0; s >>= 1) {
    const float ov = __shfl_xor(bv, s, 64);
    const int oi = __shfl_xor(bi, s, 64);
    if (ov > bv || (ov == bv && oi < bi)) { bv = ov; bi = oi; }
  }
  if (lane == 0) {
    const int slot = atomicAdd(&cnt[bi * 16], 1);
    if (slot < 1024) list[bi * 1024 + slot] = r;
  }
}

// ---------------------------------------------------------------------------
// K2: child logits from dense row lists. grid = 64 experts x 4 chunks
// (stages cW exactly once chip-wide). 4 rows batched per W pass; pair-packed
// butterfly reduce (7 shfl per 2 accumulators).
// ---------------------------------------------------------------------------
__global__ __launch_bounds__(256) void k2_child(const float* __restrict__ x,
                                                const float* __restrict__ cW,
                                                const float* __restrict__ cb,
                                                const int* __restrict__ cnt,
                                                const int* __restrict__ list,
                                                float* __restrict__ cout) {
  __shared__ float wlds[K_ * D_];  // 40 KB
  const int e   = blockIdx.x >> 2;
  const int chk = blockIdx.x & 3;
  const int tid = threadIdx.x;

  const float4* wg4 = (const float4*)(cW + (size_t)e * (K_ * D_));
  float4* wl4 = (float4*)wlds;
#pragma unroll
  for (int tI = 0; tI < 10; ++tI) wl4[tid + 256 * tI] = wg4[tid + 256 * tI];
  __syncthreads();

  const int n   = min(cnt[e * 16], 1024);
  const int per = (n + 3) >> 2;
  const int lo  = chk * per;
  const int hi  = min(lo + per, n);
  const int m   = hi - lo;
  if (m <= 0) return;

  const int wave = tid >> 6, lane = tid & 63;
  const int wper = (m + 3) >> 2;
  const int wlo  = lo + wave * wper;
  const int whi  = min(wlo + wper, hi);

  const float4* x4 = (const float4*)x;
  const int* mylist = list + e * 1024;

  for (int i0 = wlo; i0 < whi; i0 += 4) {
    const int vb = min(4, whi - i0);
    const int ra = mylist[i0];
    const int rb = mylist[i0 + min(1, vb - 1)];
    const int rc = mylist[i0 + min(2, vb - 1)];
    const int rd = mylist[i0 + min(3, vb - 1)];

    float a[20];
#pragma unroll
    for (int q = 0; q < 20; ++q) a[q] = 0.f;

#pragma unroll
    for (int tt = 0; tt < 8; ++tt) {
      const float4 xv0 = x4[(size_t)ra * 512 + lane + 64 * tt];
      const float4 xv1 = x4[(size_t)rb * 512 + lane + 64 * tt];
      const float4 xv2 = x4[(size_t)rc * 512 + lane + 64 * tt];
      const float4 xv3 = x4[(size_t)rd * 512 + lane + 64 * tt];
#pragma unroll
      for (int k = 0; k < 5; ++k) {
        const float4 wv = wl4[k * 512 + lane + 64 * tt];
        a[0 * 5 + k] += xv0.x * wv.x + xv0.y * wv.y + xv0.z * wv.z + xv0.w * wv.w;
        a[1 * 5 + k] += xv1.x * wv.x + xv1.y * wv.y + xv1.z * wv.z + xv1.w * wv.w;
        a[2 * 5 + k] += xv2.x * wv.x + xv2.y * wv.y + xv2.z * wv.z + xv2.w * wv.w;
        a[3 * 5 + k] += xv3.x * wv.x + xv3.y * wv.y + xv3.z * wv.z + xv3.w * wv.w;
      }
    }
#pragma unroll
    for (int p = 0; p < 10; ++p) {
      float va = a[2 * p], vb2 = a[2 * p + 1];
      va  += __shfl_xor(va, 32, 64);
      vb2 += __shfl_xor(vb2, 32, 64);
      float z = (lane < 32) ? va : vb2;
      z += __shfl_xor(z, 16, 64);
      z += __shfl_xor(z, 8, 64);
      z += __shfl_xor(z, 4, 64);
      z += __shfl_xor(z, 2, 64);
      z += __shfl_xor(z, 1, 64);
      a[2 * p] = z;
    }
    if (lane == 0 || lane == 32) {
      const int off = (lane == 32) ? 1 : 0;
#pragma unroll
      for (int p = 0; p < 10; ++p) {
        const int f = 2 * p + off;
        const int rr = f / 5, kk = f % 5;
        if (rr < vb) {
          const int r = (rr == 0) ? ra : (rr == 1) ? rb : (rr == 2) ? rc : rd;
          cout[(size_t)r * K_ + kk] = a[2 * p] + cb[e * K_ + kk];
        }
      }
    }
  }
}

extern "C" void kernel_launch(void* const* d_in, const int* in_sizes, int n_in,
                              void* d_out, int out_size, void* d_ws, size_t ws_size,
                              hipStream_t stream) {
  const float* x  = (const float*)d_in[0];
  const float* pW = (const float*)d_in[1];
  const float* pb = (const float*)d_in[2];
  const float* cW = (const float*)d_in[3];
  const float* cb = (const float*)d_in[4];
  float* pout = (float*)d_out;                    // [B, 64]
  float* cout = (float*)d_out + (size_t)B_ * P_;  // [B, 5]

  char* ws = (char*)d_ws;
  int*   cnt  = (int*)ws;                   // 64 counters, 64B apart (4 KB)
  int*   list = (int*)(ws + 4096);          // 64 x 1024 ints (256 KB)
  float* part = (float*)(ws + 1048576);     // KS x 4 MB = 16 MB

  hipMemsetAsync(cnt, 0, 4096, stream);
  k1_parent<<<256 * KS, 256, 0, stream>>>(x, pW, part);
  k_reduce<<<B_ / 4, 256, 0, stream>>>(part, pb, pout, cnt, list);
  k2_child<<<P_ * 4, 256, 0, stream>>>(x, cW, cb, cnt, list, cout);
}